// Round 1
// baseline (4516.360 us; speedup 1.0000x reference)
//
#include <hip/hip_runtime.h>
#include <math.h>

// ---------------- degree accumulation ----------------
__global__ void deg_kernel(const int* __restrict__ dst, const float* __restrict__ ew,
                           float* __restrict__ deg, int E) {
    int t = blockIdx.x * blockDim.x + threadIdx.x;
    if (t < E) atomicAdd(&deg[dst[t]], ew[t]);
}

// deg -> dinv in place; self-loop weight 1.0 folded in (deg+1 >= 1 > 0 always)
__global__ void dinv_kernel(float* __restrict__ deg, int n) {
    int t = blockIdx.x * blockDim.x + threadIdx.x;
    if (t < n) deg[t] = 1.0f / sqrtf(deg[t] + 1.0f);
}

// ---------------- skinny GEMM: Y[n,OUT] = X[n,128] @ W[128,OUT] ----------------
// W staged in two 64-row k-halves so static LDS stays <= 48 KB.
template<int OUT>
__global__ __launch_bounds__(256) void gemm_k128(const float* __restrict__ X,
                                                 const float* __restrict__ W,
                                                 float* __restrict__ Y, int n) {
    constexpr int ROWS = 32;
    constexpr int TPB  = 256;
    constexpr int RG   = TPB / OUT;   // row-groups of threads
    constexpr int RT   = ROWS / RG;   // rows per thread
    __shared__ float Wl[64 * OUT];
    __shared__ float Xl[ROWS * 128];

    int t = threadIdx.x;
    int row0 = blockIdx.x * ROWS;

    // stage X tile (rows row0..row0+31)
    for (int i = t * 4; i < ROWS * 128; i += TPB * 4) {
        int r = i >> 7, c = i & 127;
        int gr = row0 + r;
        float4 v = make_float4(0.f, 0.f, 0.f, 0.f);
        if (gr < n) v = *(const float4*)&X[(size_t)gr * 128 + c];
        *(float4*)&Xl[i] = v;
    }

    int col = t % OUT;
    int rg  = t / OUT;
    float acc[RT];
#pragma unroll
    for (int r = 0; r < RT; r++) acc[r] = 0.f;

    for (int h = 0; h < 128; h += 64) {
        __syncthreads();   // protects Wl reuse (and Xl completeness on first pass)
        for (int i = t * 4; i < 64 * OUT; i += TPB * 4)
            *(float4*)&Wl[i] = *(const float4*)&W[h * OUT + i];
        __syncthreads();
#pragma unroll
        for (int k = 0; k < 64; k += 4) {
            float w0 = Wl[(k + 0) * OUT + col];
            float w1 = Wl[(k + 1) * OUT + col];
            float w2 = Wl[(k + 2) * OUT + col];
            float w3 = Wl[(k + 3) * OUT + col];
#pragma unroll
            for (int r = 0; r < RT; r++) {
                float4 xv = *(float4*)&Xl[(r * RG + rg) * 128 + h + k];
                acc[r] += xv.x * w0 + xv.y * w1 + xv.z * w2 + xv.w * w3;
            }
        }
    }

#pragma unroll
    for (int r = 0; r < RT; r++) {
        int gr = row0 + r * RG + rg;
        if (gr < n) Y[(size_t)gr * OUT + col] = acc[r];
    }
}

// ---------------- edge scatter: out[dst] += H[src] * norm (atomic) ----------------
template<int C>   // channels (128 or 64); C/4 threads per edge
__global__ void scatter_kernel(const float* __restrict__ H, const int* __restrict__ src,
                               const int* __restrict__ dst, const float* __restrict__ ew,
                               const float* __restrict__ dinv, float* __restrict__ out, int E) {
    constexpr int TPE = C / 4;
    int t = blockIdx.x * blockDim.x + threadIdx.x;
    int e = t / TPE;
    int c = (t % TPE) * 4;
    if (e >= E) return;
    int s = src[e], d = dst[e];
    float norm = dinv[s] * ew[e] * dinv[d];
    float4 hv = *(const float4*)&H[(size_t)s * C + c];
    float* o = &out[(size_t)d * C + c];
    atomicAdd(o + 0, hv.x * norm);
    atomicAdd(o + 1, hv.y * norm);
    atomicAdd(o + 2, hv.z * norm);
    atomicAdd(o + 3, hv.w * norm);
}

// ---------------- self-loop + bias (+ReLU) ----------------
template<int C, bool RELU>
__global__ void finalize_kernel(float* __restrict__ B, const float* __restrict__ A,
                                const float* __restrict__ dinv, const float* __restrict__ bias,
                                int n) {
    int t = blockIdx.x * blockDim.x + threadIdx.x;
    long long i = (long long)t * 4;
    int row = (int)(i / C);
    int c = (int)(i % C);
    if (row >= n) return;
    float di = dinv[row];
    float sl = di * di;   // self-loop norm: dinv[i]*1*dinv[i]
    float4 bv = *(float4*)&B[i];
    float4 av = *(const float4*)&A[i];
    float4 bb = *(const float4*)&bias[c];
    bv.x += av.x * sl + bb.x;
    bv.y += av.y * sl + bb.y;
    bv.z += av.z * sl + bb.z;
    bv.w += av.w * sl + bb.w;
    if (RELU) {
        bv.x = fmaxf(bv.x, 0.f);
        bv.y = fmaxf(bv.y, 0.f);
        bv.z = fmaxf(bv.z, 0.f);
        bv.w = fmaxf(bv.w, 0.f);
    }
    *(float4*)&B[i] = bv;
}

// ---------------- decode: out[l] = dot(Z[a], Z[b]) over 64 channels ----------------
// 16 lanes per edge, float4 each, shuffle-reduce within the 16-lane group.
__global__ void decode_kernel(const float* __restrict__ Z, const int* __restrict__ ea,
                              const int* __restrict__ eb, float* __restrict__ out, int L) {
    int t = blockIdx.x * blockDim.x + threadIdx.x;
    int e = t >> 4;
    int c = (t & 15) << 2;
    if (e >= L) return;
    float4 za = *(const float4*)&Z[(size_t)ea[e] * 64 + c];
    float4 zb = *(const float4*)&Z[(size_t)eb[e] * 64 + c];
    float p = za.x * zb.x + za.y * zb.y + za.z * zb.z + za.w * zb.w;
    p += __shfl_xor(p, 1);
    p += __shfl_xor(p, 2);
    p += __shfl_xor(p, 4);
    p += __shfl_xor(p, 8);
    if ((t & 15) == 0) out[e] = p;
}

extern "C" void kernel_launch(void* const* d_in, const int* in_sizes, int n_in,
                              void* d_out, int out_size, void* d_ws, size_t ws_size,
                              hipStream_t stream) {
    const float* x   = (const float*)d_in[0];
    const int*   ei  = (const int*)d_in[1];   // [2,E] flat: src = ei, dst = ei+E
    const float* ew  = (const float*)d_in[2];
    const int*   eli = (const int*)d_in[3];   // [2,L] flat
    const float* W1  = (const float*)d_in[4];
    const float* b1  = (const float*)d_in[5];
    const float* W2  = (const float*)d_in[6];
    const float* b2  = (const float*)d_in[7];
    float* out = (float*)d_out;

    const int N = in_sizes[0] / 128;
    const int E = in_sizes[2];
    const int L = in_sizes[3] / 2;
    const int NP = ((N + 255) / 256) * 256;   // aligned node count for ws layout

    float* ws   = (float*)d_ws;
    float* dinv = ws;                          // NP floats (deg -> dinv in place)
    float* A    = ws + NP;                     // N*128 floats (h, later h2 in first N*64)
    float* B    = A + (size_t)NP * 128;        // N*128 floats (scatter dest / h1, later z)

    // degree + dinv
    hipMemsetAsync(dinv, 0, (size_t)N * 4, stream);
    deg_kernel<<<(E + 255) / 256, 256, 0, stream>>>(ei + E, ew, dinv, E);
    dinv_kernel<<<(N + 255) / 256, 256, 0, stream>>>(dinv, N);

    // layer 1: h = x@W1 -> A ; scatter -> B ; + self-loop + b1 + relu
    gemm_k128<128><<<(N + 31) / 32, 256, 0, stream>>>(x, W1, A, N);
    hipMemsetAsync(B, 0, (size_t)N * 128 * 4, stream);
    scatter_kernel<128><<<(E * 32 + 255) / 256, 256, 0, stream>>>(A, ei, ei + E, ew, dinv, B, E);
    finalize_kernel<128, true><<<((N * 128 / 4) + 255) / 256, 256, 0, stream>>>(B, A, dinv, b1, N);

    // layer 2: h2 = h1@W2 -> A(first N*64) ; scatter -> B(first N*64) ; + self-loop + b2
    gemm_k128<64><<<(N + 31) / 32, 256, 0, stream>>>(B, W2, A, N);
    hipMemsetAsync(B, 0, (size_t)N * 64 * 4, stream);
    scatter_kernel<64><<<(E * 16 + 255) / 256, 256, 0, stream>>>(A, ei, ei + E, ew, dinv, B, E);
    finalize_kernel<64, false><<<((N * 64 / 4) + 255) / 256, 256, 0, stream>>>(B, A, dinv, b2, N);

    // decode
    decode_kernel<<<(L * 16 + 255) / 256, 256, 0, stream>>>(B, eli, eli + L, out, L);
}

// Round 2
// 796.338 us; speedup vs baseline: 5.6714x; 5.6714x over previous
//
#include <hip/hip_runtime.h>
#include <math.h>

// ---------------- degree accumulation (float atomics on 400KB -> L2-resident, cheap) ----------------
__global__ void deg_kernel(const int* __restrict__ dst, const float* __restrict__ ew,
                           float* __restrict__ deg, int E) {
    int t = blockIdx.x * blockDim.x + threadIdx.x;
    if (t < E) atomicAdd(&deg[dst[t]], ew[t]);
}

__global__ void dinv_kernel(float* __restrict__ deg, int n) {
    int t = blockIdx.x * blockDim.x + threadIdx.x;
    if (t < n) deg[t] = 1.0f / sqrtf(deg[t] + 1.0f);  // self-loop weight folded in
}

// ---------------- counting sort: histogram ----------------
__global__ void hist_kernel(const int* __restrict__ dst, int* __restrict__ cnt, int E) {
    int t = blockIdx.x * blockDim.x + threadIdx.x;
    if (t < E) atomicAdd(&cnt[dst[t]], 1);
}

// exclusive scan, stage 1: per-block (1024 elems / 256 threads) exclusive values + block sums
__global__ __launch_bounds__(256) void scan_block(const int* __restrict__ in, int* __restrict__ out,
                                                  int* __restrict__ bsum, int n) {
    __shared__ int s[256];
    int tid = threadIdx.x;
    int base = blockIdx.x * 1024 + tid * 4;
    int a0 = (base + 0 < n) ? in[base + 0] : 0;
    int a1 = (base + 1 < n) ? in[base + 1] : 0;
    int a2 = (base + 2 < n) ? in[base + 2] : 0;
    int a3 = (base + 3 < n) ? in[base + 3] : 0;
    int tsum = a0 + a1 + a2 + a3;
    s[tid] = tsum;
    __syncthreads();
    for (int off = 1; off < 256; off <<= 1) {
        int v = (tid >= off) ? s[tid - off] : 0;
        __syncthreads();
        s[tid] += v;
        __syncthreads();
    }
    int texcl = s[tid] - tsum;
    if (base + 0 < n) out[base + 0] = texcl;
    if (base + 1 < n) out[base + 1] = texcl + a0;
    if (base + 2 < n) out[base + 2] = texcl + a0 + a1;
    if (base + 3 < n) out[base + 3] = texcl + a0 + a1 + a2;
    if (tid == 255) bsum[blockIdx.x] = s[255];
}

// stage 2: exclusive scan of block sums (single block, chunked with carry)
__global__ __launch_bounds__(256) void scan_bsums(int* __restrict__ bsum, int nb) {
    __shared__ int s[256];
    __shared__ int carry_s;
    int tid = threadIdx.x;
    if (tid == 0) carry_s = 0;
    __syncthreads();
    for (int base = 0; base < nb; base += 256) {
        int v = (base + tid < nb) ? bsum[base + tid] : 0;
        int orig = v;
        s[tid] = v;
        __syncthreads();
        for (int off = 1; off < 256; off <<= 1) {
            int u = (tid >= off) ? s[tid - off] : 0;
            __syncthreads();
            s[tid] += u;
            __syncthreads();
        }
        int carry = carry_s;
        int excl = s[tid] - orig + carry;
        if (base + tid < nb) bsum[base + tid] = excl;
        int tot = s[255];
        __syncthreads();
        if (tid == 0) carry_s = carry + tot;
        __syncthreads();
    }
}

// stage 3: add block offsets
__global__ void scan_add(int* __restrict__ rowptr, const int* __restrict__ bscan, int n) {
    int t = blockIdx.x * blockDim.x + threadIdx.x;
    if (t < n) rowptr[t] += bscan[t >> 10];
}

__global__ void copy_int(const int* __restrict__ a, int* __restrict__ b, int n) {
    int t = blockIdx.x * blockDim.x + threadIdx.x;
    if (t < n) b[t] = a[t];
}

// position scatter: sort (src, norm) by dst into CSR order
__global__ void build_csr(const int* __restrict__ src, const int* __restrict__ dst,
                          const float* __restrict__ ew, const float* __restrict__ dinv,
                          int* __restrict__ pos, int* __restrict__ s_srt,
                          float* __restrict__ n_srt, int E) {
    int e = blockIdx.x * blockDim.x + threadIdx.x;
    if (e >= E) return;
    int d = dst[e], s = src[e];
    int p = atomicAdd(&pos[d], 1);
    s_srt[p] = s;
    n_srt[p] = dinv[s] * ew[e] * dinv[d];
}

// ---------------- skinny GEMM: Y[n,OUT] = X[n,128] @ W[128,OUT] ----------------
template<int OUT>
__global__ __launch_bounds__(256) void gemm_k128(const float* __restrict__ X,
                                                 const float* __restrict__ W,
                                                 float* __restrict__ Y, int n) {
    constexpr int ROWS = 32;
    constexpr int TPB  = 256;
    constexpr int RG   = TPB / OUT;
    constexpr int RT   = ROWS / RG;
    __shared__ float Wl[64 * OUT];
    __shared__ float Xl[ROWS * 128];

    int t = threadIdx.x;
    int row0 = blockIdx.x * ROWS;

    for (int i = t * 4; i < ROWS * 128; i += TPB * 4) {
        int r = i >> 7, c = i & 127;
        int gr = row0 + r;
        float4 v = make_float4(0.f, 0.f, 0.f, 0.f);
        if (gr < n) v = *(const float4*)&X[(size_t)gr * 128 + c];
        *(float4*)&Xl[i] = v;
    }

    int col = t % OUT;
    int rg  = t / OUT;
    float acc[RT];
#pragma unroll
    for (int r = 0; r < RT; r++) acc[r] = 0.f;

    for (int h = 0; h < 128; h += 64) {
        __syncthreads();
        for (int i = t * 4; i < 64 * OUT; i += TPB * 4)
            *(float4*)&Wl[i] = *(const float4*)&W[h * OUT + i];
        __syncthreads();
#pragma unroll
        for (int k = 0; k < 64; k += 4) {
            float w0 = Wl[(k + 0) * OUT + col];
            float w1 = Wl[(k + 1) * OUT + col];
            float w2 = Wl[(k + 2) * OUT + col];
            float w3 = Wl[(k + 3) * OUT + col];
#pragma unroll
            for (int r = 0; r < RT; r++) {
                float4 xv = *(float4*)&Xl[(r * RG + rg) * 128 + h + k];
                acc[r] += xv.x * w0 + xv.y * w1 + xv.z * w2 + xv.w * w3;
            }
        }
    }

#pragma unroll
    for (int r = 0; r < RT; r++) {
        int gr = row0 + r * RG + rg;
        if (gr < n) Y[(size_t)gr * OUT + col] = acc[r];
    }
}

// ---------------- CSR segmented gather-reduce + fused epilogue ----------------
// C/4 threads per node; each thread owns 4 channels, loops over the node's in-edges.
template<int C, bool RELU>
__global__ __launch_bounds__(256) void gather_reduce(const float* __restrict__ H,
                                                     const int* __restrict__ rowptr,
                                                     const int* __restrict__ s_srt,
                                                     const float* __restrict__ n_srt,
                                                     const float* __restrict__ dinv,
                                                     const float* __restrict__ bias,
                                                     float* __restrict__ out, int n) {
    constexpr int TPN = C / 4;
    int t = blockIdx.x * blockDim.x + threadIdx.x;
    int node = t / TPN;
    int c = (t % TPN) * 4;
    if (node >= n) return;
    int beg = rowptr[node], end = rowptr[node + 1];
    float di = dinv[node];
    float sl = di * di;   // self-loop norm
    float4 hv = *(const float4*)&H[(size_t)node * C + c];
    float4 bb = *(const float4*)&bias[c];
    float4 acc;
    acc.x = hv.x * sl + bb.x;
    acc.y = hv.y * sl + bb.y;
    acc.z = hv.z * sl + bb.z;
    acc.w = hv.w * sl + bb.w;
    for (int j = beg; j < end; j++) {
        int s = s_srt[j];
        float w = n_srt[j];
        float4 v = *(const float4*)&H[(size_t)s * C + c];
        acc.x += v.x * w;
        acc.y += v.y * w;
        acc.z += v.z * w;
        acc.w += v.w * w;
    }
    if (RELU) {
        acc.x = fmaxf(acc.x, 0.f);
        acc.y = fmaxf(acc.y, 0.f);
        acc.z = fmaxf(acc.z, 0.f);
        acc.w = fmaxf(acc.w, 0.f);
    }
    *(float4*)&out[(size_t)node * C + c] = acc;
}

// ---------------- decode ----------------
__global__ void decode_kernel(const float* __restrict__ Z, const int* __restrict__ ea,
                              const int* __restrict__ eb, float* __restrict__ out, int L) {
    int t = blockIdx.x * blockDim.x + threadIdx.x;
    int e = t >> 4;
    int c = (t & 15) << 2;
    if (e >= L) return;
    float4 za = *(const float4*)&Z[(size_t)ea[e] * 64 + c];
    float4 zb = *(const float4*)&Z[(size_t)eb[e] * 64 + c];
    float p = za.x * zb.x + za.y * zb.y + za.z * zb.z + za.w * zb.w;
    p += __shfl_xor(p, 1);
    p += __shfl_xor(p, 2);
    p += __shfl_xor(p, 4);
    p += __shfl_xor(p, 8);
    if ((t & 15) == 0) out[e] = p;
}

extern "C" void kernel_launch(void* const* d_in, const int* in_sizes, int n_in,
                              void* d_out, int out_size, void* d_ws, size_t ws_size,
                              hipStream_t stream) {
    const float* x   = (const float*)d_in[0];
    const int*   ei  = (const int*)d_in[1];   // [2,E] flat: src = ei, dst = ei+E
    const float* ew  = (const float*)d_in[2];
    const int*   eli = (const int*)d_in[3];   // [2,L] flat
    const float* W1  = (const float*)d_in[4];
    const float* b1  = (const float*)d_in[5];
    const float* W2  = (const float*)d_in[6];
    const float* b2  = (const float*)d_in[7];
    float* out = (float*)d_out;

    const int N = in_sizes[0] / 128;
    const int E = in_sizes[2];
    const int L = in_sizes[3] / 2;
    const int NP = ((N + 255) / 256) * 256;

    // ws layout (4B words)
    float* ws     = (float*)d_ws;
    float* dinv   = ws;                                  // NP
    int*   cnt    = (int*)(ws + NP);                     // NP (needs N+1)
    int*   rowptr = cnt + NP;                            // NP (needs N+1)
    int*   pos    = rowptr + NP;                         // NP
    int*   bsum   = pos + NP;                            // 1024
    int*   s_srt  = bsum + 1024;                         // E
    float* n_srt  = (float*)(s_srt + E);                 // E
    float* A      = n_srt + E;                           // NP*128
    float* B      = A + (size_t)NP * 128;                // NP*128

    const int n1 = N + 1;
    const int nb = (n1 + 1023) / 1024;

    // degree + dinv
    hipMemsetAsync(dinv, 0, (size_t)N * 4, stream);
    hipMemsetAsync(cnt, 0, (size_t)n1 * 4, stream);
    deg_kernel<<<(E + 255) / 256, 256, 0, stream>>>(ei + E, ew, dinv, E);
    dinv_kernel<<<(N + 255) / 256, 256, 0, stream>>>(dinv, N);

    // CSR build (counting sort by dst); reused by both layers
    hist_kernel<<<(E + 255) / 256, 256, 0, stream>>>(ei + E, cnt, E);
    scan_block<<<nb, 256, 0, stream>>>(cnt, rowptr, bsum, n1);
    scan_bsums<<<1, 256, 0, stream>>>(bsum, nb);
    scan_add<<<(n1 + 255) / 256, 256, 0, stream>>>(rowptr, bsum, n1);
    copy_int<<<(N + 255) / 256, 256, 0, stream>>>(rowptr, pos, N);
    build_csr<<<(E + 255) / 256, 256, 0, stream>>>(ei, ei + E, ew, dinv, pos, s_srt, n_srt, E);

    // layer 1: h = x@W1 -> A ; segmented reduce + self-loop + b1 + relu -> B
    gemm_k128<128><<<(N + 31) / 32, 256, 0, stream>>>(x, W1, A, N);
    gather_reduce<128, true><<<(N * 32 + 255) / 256, 256, 0, stream>>>(A, rowptr, s_srt, n_srt, dinv, b1, B, N);

    // layer 2: h2 = h1@W2 -> A ; segmented reduce + self-loop + b2 -> B
    gemm_k128<64><<<(N + 31) / 32, 256, 0, stream>>>(B, W2, A, N);
    gather_reduce<64, false><<<(N * 16 + 255) / 256, 256, 0, stream>>>(A, rowptr, s_srt, n_srt, dinv, b2, B, N);

    // decode
    decode_kernel<<<(L * 16 + 255) / 256, 256, 0, stream>>>(B, eli, eli + L, out, L);
}

// Round 3
// 694.876 us; speedup vs baseline: 6.4995x; 1.1460x over previous
//
#include <hip/hip_runtime.h>
#include <math.h>

// ---------------- degree accumulation ----------------
__global__ void deg_kernel(const int* __restrict__ dst, const float* __restrict__ ew,
                           float* __restrict__ deg, int E) {
    int t = blockIdx.x * blockDim.x + threadIdx.x;
    if (t < E) atomicAdd(&deg[dst[t]], ew[t]);
}

__global__ void dinv_kernel(float* __restrict__ deg, int n) {
    int t = blockIdx.x * blockDim.x + threadIdx.x;
    if (t < n) deg[t] = 1.0f / sqrtf(deg[t] + 1.0f);  // self-loop weight folded in
}

// ---------------- counting sort: histogram ----------------
__global__ void hist_kernel(const int* __restrict__ dst, int* __restrict__ cnt, int E) {
    int t = blockIdx.x * blockDim.x + threadIdx.x;
    if (t < E) atomicAdd(&cnt[dst[t]], 1);
}

// exclusive scan, stage 1
__global__ __launch_bounds__(256) void scan_block(const int* __restrict__ in, int* __restrict__ out,
                                                  int* __restrict__ bsum, int n) {
    __shared__ int s[256];
    int tid = threadIdx.x;
    int base = blockIdx.x * 1024 + tid * 4;
    int a0 = (base + 0 < n) ? in[base + 0] : 0;
    int a1 = (base + 1 < n) ? in[base + 1] : 0;
    int a2 = (base + 2 < n) ? in[base + 2] : 0;
    int a3 = (base + 3 < n) ? in[base + 3] : 0;
    int tsum = a0 + a1 + a2 + a3;
    s[tid] = tsum;
    __syncthreads();
    for (int off = 1; off < 256; off <<= 1) {
        int v = (tid >= off) ? s[tid - off] : 0;
        __syncthreads();
        s[tid] += v;
        __syncthreads();
    }
    int texcl = s[tid] - tsum;
    if (base + 0 < n) out[base + 0] = texcl;
    if (base + 1 < n) out[base + 1] = texcl + a0;
    if (base + 2 < n) out[base + 2] = texcl + a0 + a1;
    if (base + 3 < n) out[base + 3] = texcl + a0 + a1 + a2;
    if (tid == 255) bsum[blockIdx.x] = s[255];
}

// stage 2: exclusive scan of block sums
__global__ __launch_bounds__(256) void scan_bsums(int* __restrict__ bsum, int nb) {
    __shared__ int s[256];
    __shared__ int carry_s;
    int tid = threadIdx.x;
    if (tid == 0) carry_s = 0;
    __syncthreads();
    for (int base = 0; base < nb; base += 256) {
        int v = (base + tid < nb) ? bsum[base + tid] : 0;
        int orig = v;
        s[tid] = v;
        __syncthreads();
        for (int off = 1; off < 256; off <<= 1) {
            int u = (tid >= off) ? s[tid - off] : 0;
            __syncthreads();
            s[tid] += u;
            __syncthreads();
        }
        int carry = carry_s;
        int excl = s[tid] - orig + carry;
        if (base + tid < nb) bsum[base + tid] = excl;
        int tot = s[255];
        __syncthreads();
        if (tid == 0) carry_s = carry + tot;
        __syncthreads();
    }
}

// stage 3: add block offsets
__global__ void scan_add(int* __restrict__ rowptr, const int* __restrict__ bscan, int n) {
    int t = blockIdx.x * blockDim.x + threadIdx.x;
    if (t < n) rowptr[t] += bscan[t >> 10];
}

__global__ void copy_int(const int* __restrict__ a, int* __restrict__ b, int n) {
    int t = blockIdx.x * blockDim.x + threadIdx.x;
    if (t < n) b[t] = a[t];
}

// position scatter: sort (src, norm) by dst into CSR order
__global__ void build_csr(const int* __restrict__ src, const int* __restrict__ dst,
                          const float* __restrict__ ew, const float* __restrict__ dinv,
                          int* __restrict__ pos, int* __restrict__ s_srt,
                          float* __restrict__ n_srt, int E) {
    int e = blockIdx.x * blockDim.x + threadIdx.x;
    if (e >= E) return;
    int d = dst[e], s = src[e];
    int p = atomicAdd(&pos[d], 1);
    s_srt[p] = s;
    n_srt[p] = dinv[s] * ew[e] * dinv[d];
}

// ---------------- register-tiled GEMM: Y[n,OUT] = X[n,128] @ W[128,OUT] ----------------
// 64-row tile; thread owns RT rows x 4 cols of fp32 accumulators (outer product).
// X staged full-K row-major (pad+4: b128-aligned, <=2-way banks); W staged in K=32 chunks.
template<int OUT>
__global__ __launch_bounds__(256) void gemm_rt(const float* __restrict__ X,
                                               const float* __restrict__ W,
                                               float* __restrict__ Y, int n) {
    constexpr int CG  = OUT / 4;    // col-groups (threads across cols): 32 or 16
    constexpr int RG  = 256 / CG;   // row-groups: 8 or 16
    constexpr int M   = 64;
    constexpr int RT  = M / RG;     // rows per thread: 8 or 4
    constexpr int KC  = 32;
    constexpr int LDX = 132;        // 128 + 4 pad
    __shared__ float  Xl[M * LDX];
    __shared__ float4 Wl[KC * CG];

    int t = threadIdx.x;
    int row0 = blockIdx.x * M;

    // stage X tile: M rows x 128 cols, direct float4 copies (coalesced, conflict-free)
    {
        const float4* Xg = (const float4*)X;
        for (int f = t; f < M * 32; f += 256) {
            int r = f >> 5, c4 = f & 31;
            int gr = row0 + r;
            float4 v = make_float4(0.f, 0.f, 0.f, 0.f);
            if (gr < n) v = Xg[(size_t)gr * 32 + c4];
            *(float4*)&Xl[r * LDX + c4 * 4] = v;
        }
    }

    int cg = t % CG;
    int r0 = (t / CG) * RT;

    float4 acc[RT];
#pragma unroll
    for (int r = 0; r < RT; r++) acc[r] = make_float4(0.f, 0.f, 0.f, 0.f);

    const float4* Wg = (const float4*)W;
    for (int kc = 0; kc < 128; kc += KC) {
        __syncthreads();
        for (int f = t; f < KC * CG; f += 256)
            Wl[f] = Wg[(size_t)kc * CG + f];
        __syncthreads();
#pragma unroll 4
        for (int k = 0; k < KC; k += 4) {
            float4 b0 = Wl[(k + 0) * CG + cg];
            float4 b1 = Wl[(k + 1) * CG + cg];
            float4 b2 = Wl[(k + 2) * CG + cg];
            float4 b3 = Wl[(k + 3) * CG + cg];
#pragma unroll
            for (int r = 0; r < RT; r++) {
                float4 a = *(float4*)&Xl[(r0 + r) * LDX + kc + k];
                acc[r].x += a.x * b0.x + a.y * b1.x + a.z * b2.x + a.w * b3.x;
                acc[r].y += a.x * b0.y + a.y * b1.y + a.z * b2.y + a.w * b3.y;
                acc[r].z += a.x * b0.z + a.y * b1.z + a.z * b2.z + a.w * b3.z;
                acc[r].w += a.x * b0.w + a.y * b1.w + a.z * b2.w + a.w * b3.w;
            }
        }
    }

#pragma unroll
    for (int r = 0; r < RT; r++) {
        int gr = row0 + r0 + r;
        if (gr < n) *(float4*)&Y[(size_t)gr * OUT + cg * 4] = acc[r];
    }
}

// ---------------- CSR segmented gather-reduce + fused epilogue ----------------
template<int C, bool RELU>
__global__ __launch_bounds__(256) void gather_reduce(const float* __restrict__ H,
                                                     const int* __restrict__ rowptr,
                                                     const int* __restrict__ s_srt,
                                                     const float* __restrict__ n_srt,
                                                     const float* __restrict__ dinv,
                                                     const float* __restrict__ bias,
                                                     float* __restrict__ out, int n) {
    constexpr int TPN = C / 4;
    int t = blockIdx.x * blockDim.x + threadIdx.x;
    int node = t / TPN;
    int c = (t % TPN) * 4;
    if (node >= n) return;
    int beg = rowptr[node], end = rowptr[node + 1];
    float di = dinv[node];
    float sl = di * di;
    float4 hv = *(const float4*)&H[(size_t)node * C + c];
    float4 bb = *(const float4*)&bias[c];
    float4 acc;
    acc.x = hv.x * sl + bb.x;
    acc.y = hv.y * sl + bb.y;
    acc.z = hv.z * sl + bb.z;
    acc.w = hv.w * sl + bb.w;
    for (int j = beg; j < end; j++) {
        int s = s_srt[j];
        float w = n_srt[j];
        float4 v = *(const float4*)&H[(size_t)s * C + c];
        acc.x += v.x * w;
        acc.y += v.y * w;
        acc.z += v.z * w;
        acc.w += v.w * w;
    }
    if (RELU) {
        acc.x = fmaxf(acc.x, 0.f);
        acc.y = fmaxf(acc.y, 0.f);
        acc.z = fmaxf(acc.z, 0.f);
        acc.w = fmaxf(acc.w, 0.f);
    }
    *(float4*)&out[(size_t)node * C + c] = acc;
}

// ---------------- decode ----------------
__global__ void decode_kernel(const float* __restrict__ Z, const int* __restrict__ ea,
                              const int* __restrict__ eb, float* __restrict__ out, int L) {
    int t = blockIdx.x * blockDim.x + threadIdx.x;
    int e = t >> 4;
    int c = (t & 15) << 2;
    if (e >= L) return;
    float4 za = *(const float4*)&Z[(size_t)ea[e] * 64 + c];
    float4 zb = *(const float4*)&Z[(size_t)eb[e] * 64 + c];
    float p = za.x * zb.x + za.y * zb.y + za.z * zb.z + za.w * zb.w;
    p += __shfl_xor(p, 1);
    p += __shfl_xor(p, 2);
    p += __shfl_xor(p, 4);
    p += __shfl_xor(p, 8);
    if ((t & 15) == 0) out[e] = p;
}

extern "C" void kernel_launch(void* const* d_in, const int* in_sizes, int n_in,
                              void* d_out, int out_size, void* d_ws, size_t ws_size,
                              hipStream_t stream) {
    const float* x   = (const float*)d_in[0];
    const int*   ei  = (const int*)d_in[1];   // [2,E] flat: src = ei, dst = ei+E
    const float* ew  = (const float*)d_in[2];
    const int*   eli = (const int*)d_in[3];   // [2,L] flat
    const float* W1  = (const float*)d_in[4];
    const float* b1  = (const float*)d_in[5];
    const float* W2  = (const float*)d_in[6];
    const float* b2  = (const float*)d_in[7];
    float* out = (float*)d_out;

    const int N = in_sizes[0] / 128;
    const int E = in_sizes[2];
    const int L = in_sizes[3] / 2;
    const int NP = ((N + 255) / 256) * 256;

    float* ws     = (float*)d_ws;
    float* dinv   = ws;                                  // NP
    int*   cnt    = (int*)(ws + NP);                     // NP (needs N+1)
    int*   rowptr = cnt + NP;                            // NP (needs N+1)
    int*   pos    = rowptr + NP;                         // NP
    int*   bsum   = pos + NP;                            // 1024
    int*   s_srt  = bsum + 1024;                         // E
    float* n_srt  = (float*)(s_srt + E);                 // E
    float* A      = n_srt + E;                           // NP*128
    float* B      = A + (size_t)NP * 128;                // NP*128

    const int n1 = N + 1;
    const int nb = (n1 + 1023) / 1024;

    hipMemsetAsync(dinv, 0, (size_t)N * 4, stream);
    hipMemsetAsync(cnt, 0, (size_t)n1 * 4, stream);
    deg_kernel<<<(E + 255) / 256, 256, 0, stream>>>(ei + E, ew, dinv, E);
    dinv_kernel<<<(N + 255) / 256, 256, 0, stream>>>(dinv, N);

    hist_kernel<<<(E + 255) / 256, 256, 0, stream>>>(ei + E, cnt, E);
    scan_block<<<nb, 256, 0, stream>>>(cnt, rowptr, bsum, n1);
    scan_bsums<<<1, 256, 0, stream>>>(bsum, nb);
    scan_add<<<(n1 + 255) / 256, 256, 0, stream>>>(rowptr, bsum, n1);
    copy_int<<<(N + 255) / 256, 256, 0, stream>>>(rowptr, pos, N);
    build_csr<<<(E + 255) / 256, 256, 0, stream>>>(ei, ei + E, ew, dinv, pos, s_srt, n_srt, E);

    // layer 1
    gemm_rt<128><<<(N + 63) / 64, 256, 0, stream>>>(x, W1, A, N);
    gather_reduce<128, true><<<(N * 32 + 255) / 256, 256, 0, stream>>>(A, rowptr, s_srt, n_srt, dinv, b1, B, N);

    // layer 2
    gemm_rt<64><<<(N + 63) / 64, 256, 0, stream>>>(B, W2, A, N);
    gather_reduce<64, false><<<(N * 16 + 255) / 256, 256, 0, stream>>>(A, rowptr, s_srt, n_srt, dinv, b2, B, N);

    // decode
    decode_kernel<<<(L * 16 + 255) / 256, 256, 0, stream>>>(B, eli, eli + L, out, L);
}

// Round 4
// 638.644 us; speedup vs baseline: 7.0718x; 1.0880x over previous
//
#include <hip/hip_runtime.h>
#include <math.h>

// ---------------- fused degree + histogram (one pass over dst) ----------------
__global__ void deg_hist_kernel(const int* __restrict__ dst, const float* __restrict__ ew,
                                float* __restrict__ deg, int* __restrict__ cnt, int E) {
    int t = blockIdx.x * blockDim.x + threadIdx.x;
    if (t < E) {
        int d = dst[t];
        atomicAdd(&deg[d], ew[t]);
        atomicAdd(&cnt[d], 1);
    }
}

__global__ void dinv_kernel(float* __restrict__ deg, int n) {
    int t = blockIdx.x * blockDim.x + threadIdx.x;
    if (t < n) deg[t] = 1.0f / sqrtf(deg[t] + 1.0f);  // self-loop weight folded in
}

// exclusive scan, stage 1
__global__ __launch_bounds__(256) void scan_block(const int* __restrict__ in, int* __restrict__ out,
                                                  int* __restrict__ bsum, int n) {
    __shared__ int s[256];
    int tid = threadIdx.x;
    int base = blockIdx.x * 1024 + tid * 4;
    int a0 = (base + 0 < n) ? in[base + 0] : 0;
    int a1 = (base + 1 < n) ? in[base + 1] : 0;
    int a2 = (base + 2 < n) ? in[base + 2] : 0;
    int a3 = (base + 3 < n) ? in[base + 3] : 0;
    int tsum = a0 + a1 + a2 + a3;
    s[tid] = tsum;
    __syncthreads();
    for (int off = 1; off < 256; off <<= 1) {
        int v = (tid >= off) ? s[tid - off] : 0;
        __syncthreads();
        s[tid] += v;
        __syncthreads();
    }
    int texcl = s[tid] - tsum;
    if (base + 0 < n) out[base + 0] = texcl;
    if (base + 1 < n) out[base + 1] = texcl + a0;
    if (base + 2 < n) out[base + 2] = texcl + a0 + a1;
    if (base + 3 < n) out[base + 3] = texcl + a0 + a1 + a2;
    if (tid == 255) bsum[blockIdx.x] = s[255];
}

// stage 2: exclusive scan of block sums
__global__ __launch_bounds__(256) void scan_bsums(int* __restrict__ bsum, int nb) {
    __shared__ int s[256];
    __shared__ int carry_s;
    int tid = threadIdx.x;
    if (tid == 0) carry_s = 0;
    __syncthreads();
    for (int base = 0; base < nb; base += 256) {
        int v = (base + tid < nb) ? bsum[base + tid] : 0;
        int orig = v;
        s[tid] = v;
        __syncthreads();
        for (int off = 1; off < 256; off <<= 1) {
            int u = (tid >= off) ? s[tid - off] : 0;
            __syncthreads();
            s[tid] += u;
            __syncthreads();
        }
        int carry = carry_s;
        int excl = s[tid] - orig + carry;
        if (base + tid < nb) bsum[base + tid] = excl;
        int tot = s[255];
        __syncthreads();
        if (tid == 0) carry_s = carry + tot;
        __syncthreads();
    }
}

// stage 3: add block offsets
__global__ void scan_add(int* __restrict__ rowptr, const int* __restrict__ bscan, int n) {
    int t = blockIdx.x * blockDim.x + threadIdx.x;
    if (t < n) rowptr[t] += bscan[t >> 10];
}

__global__ void copy_int(const int* __restrict__ a, int* __restrict__ b, int n) {
    int t = blockIdx.x * blockDim.x + threadIdx.x;
    if (t < n) b[t] = a[t];
}

// position scatter: sort (src, norm) by dst into CSR order
__global__ void build_csr(const int* __restrict__ src, const int* __restrict__ dst,
                          const float* __restrict__ ew, const float* __restrict__ dinv,
                          int* __restrict__ pos, int* __restrict__ s_srt,
                          float* __restrict__ n_srt, int E) {
    int e = blockIdx.x * blockDim.x + threadIdx.x;
    if (e >= E) return;
    int d = dst[e], s = src[e];
    int p = atomicAdd(&pos[d], 1);
    s_srt[p] = s;
    n_srt[p] = dinv[s] * ew[e] * dinv[d];
}

// ---------------- register-tiled GEMM: Y[n,OUT] = X[n,128] @ W[128,OUT] ----------------
template<int OUT>
__global__ __launch_bounds__(256) void gemm_rt(const float* __restrict__ X,
                                               const float* __restrict__ W,
                                               float* __restrict__ Y, int n) {
    constexpr int CG  = OUT / 4;
    constexpr int RG  = 256 / CG;
    constexpr int M   = 64;
    constexpr int RT  = M / RG;
    constexpr int KC  = 32;
    constexpr int LDX = 132;
    __shared__ float  Xl[M * LDX];
    __shared__ float4 Wl[KC * CG];

    int t = threadIdx.x;
    int row0 = blockIdx.x * M;

    {
        const float4* Xg = (const float4*)X;
        for (int f = t; f < M * 32; f += 256) {
            int r = f >> 5, c4 = f & 31;
            int gr = row0 + r;
            float4 v = make_float4(0.f, 0.f, 0.f, 0.f);
            if (gr < n) v = Xg[(size_t)gr * 32 + c4];
            *(float4*)&Xl[r * LDX + c4 * 4] = v;
        }
    }

    int cg = t % CG;
    int r0 = (t / CG) * RT;

    float4 acc[RT];
#pragma unroll
    for (int r = 0; r < RT; r++) acc[r] = make_float4(0.f, 0.f, 0.f, 0.f);

    const float4* Wg = (const float4*)W;
    for (int kc = 0; kc < 128; kc += KC) {
        __syncthreads();
        for (int f = t; f < KC * CG; f += 256)
            Wl[f] = Wg[(size_t)kc * CG + f];
        __syncthreads();
#pragma unroll 4
        for (int k = 0; k < KC; k += 4) {
            float4 b0 = Wl[(k + 0) * CG + cg];
            float4 b1 = Wl[(k + 1) * CG + cg];
            float4 b2 = Wl[(k + 2) * CG + cg];
            float4 b3 = Wl[(k + 3) * CG + cg];
#pragma unroll
            for (int r = 0; r < RT; r++) {
                float4 a = *(float4*)&Xl[(r0 + r) * LDX + kc + k];
                acc[r].x += a.x * b0.x + a.y * b1.x + a.z * b2.x + a.w * b3.x;
                acc[r].y += a.x * b0.y + a.y * b1.y + a.z * b2.y + a.w * b3.y;
                acc[r].z += a.x * b0.z + a.y * b1.z + a.z * b2.z + a.w * b3.z;
                acc[r].w += a.x * b0.w + a.y * b1.w + a.z * b2.w + a.w * b3.w;
            }
        }
    }

#pragma unroll
    for (int r = 0; r < RT; r++) {
        int gr = row0 + r0 + r;
        if (gr < n) *(float4*)&Y[(size_t)gr * OUT + cg * 4] = acc[r];
    }
}

// ---------------- CSR segmented gather-reduce, 4x unrolled for MLP ----------------
// C/4 threads per node; 4 independent accumulators keep 4 random gathers in flight.
template<int C, bool RELU>
__global__ __launch_bounds__(256) void gather_reduce(const float* __restrict__ H,
                                                     const int* __restrict__ rowptr,
                                                     const int* __restrict__ s_srt,
                                                     const float* __restrict__ n_srt,
                                                     const float* __restrict__ dinv,
                                                     const float* __restrict__ bias,
                                                     float* __restrict__ out, int n) {
    constexpr int TPN = C / 4;
    int t = blockIdx.x * blockDim.x + threadIdx.x;
    int node = t / TPN;
    int c = (t % TPN) * 4;
    if (node >= n) return;
    int beg = rowptr[node], end = rowptr[node + 1];
    float di = dinv[node];
    float sl = di * di;
    float4 hv = *(const float4*)&H[(size_t)node * C + c];
    float4 bb = *(const float4*)&bias[c];
    float4 a0, a1, a2, a3;
    a0.x = hv.x * sl + bb.x;
    a0.y = hv.y * sl + bb.y;
    a0.z = hv.z * sl + bb.z;
    a0.w = hv.w * sl + bb.w;
    a1 = make_float4(0.f, 0.f, 0.f, 0.f);
    a2 = make_float4(0.f, 0.f, 0.f, 0.f);
    a3 = make_float4(0.f, 0.f, 0.f, 0.f);
    int j = beg;
    for (; j + 4 <= end; j += 4) {
        int s0 = s_srt[j + 0], s1 = s_srt[j + 1], s2 = s_srt[j + 2], s3 = s_srt[j + 3];
        float w0 = n_srt[j + 0], w1 = n_srt[j + 1], w2 = n_srt[j + 2], w3 = n_srt[j + 3];
        float4 v0 = *(const float4*)&H[(size_t)s0 * C + c];
        float4 v1 = *(const float4*)&H[(size_t)s1 * C + c];
        float4 v2 = *(const float4*)&H[(size_t)s2 * C + c];
        float4 v3 = *(const float4*)&H[(size_t)s3 * C + c];
        a0.x += v0.x * w0; a0.y += v0.y * w0; a0.z += v0.z * w0; a0.w += v0.w * w0;
        a1.x += v1.x * w1; a1.y += v1.y * w1; a1.z += v1.z * w1; a1.w += v1.w * w1;
        a2.x += v2.x * w2; a2.y += v2.y * w2; a2.z += v2.z * w2; a2.w += v2.w * w2;
        a3.x += v3.x * w3; a3.y += v3.y * w3; a3.z += v3.z * w3; a3.w += v3.w * w3;
    }
    for (; j < end; j++) {
        int s = s_srt[j];
        float w = n_srt[j];
        float4 v = *(const float4*)&H[(size_t)s * C + c];
        a0.x += v.x * w; a0.y += v.y * w; a0.z += v.z * w; a0.w += v.w * w;
    }
    float4 acc;
    acc.x = (a0.x + a1.x) + (a2.x + a3.x);
    acc.y = (a0.y + a1.y) + (a2.y + a3.y);
    acc.z = (a0.z + a1.z) + (a2.z + a3.z);
    acc.w = (a0.w + a1.w) + (a2.w + a3.w);
    if (RELU) {
        acc.x = fmaxf(acc.x, 0.f);
        acc.y = fmaxf(acc.y, 0.f);
        acc.z = fmaxf(acc.z, 0.f);
        acc.w = fmaxf(acc.w, 0.f);
    }
    *(float4*)&out[(size_t)node * C + c] = acc;
}

// ---------------- decode ----------------
__global__ void decode_kernel(const float* __restrict__ Z, const int* __restrict__ ea,
                              const int* __restrict__ eb, float* __restrict__ out, int L) {
    int t = blockIdx.x * blockDim.x + threadIdx.x;
    int e = t >> 4;
    int c = (t & 15) << 2;
    if (e >= L) return;
    float4 za = *(const float4*)&Z[(size_t)ea[e] * 64 + c];
    float4 zb = *(const float4*)&Z[(size_t)eb[e] * 64 + c];
    float p = za.x * zb.x + za.y * zb.y + za.z * zb.z + za.w * zb.w;
    p += __shfl_xor(p, 1);
    p += __shfl_xor(p, 2);
    p += __shfl_xor(p, 4);
    p += __shfl_xor(p, 8);
    if ((t & 15) == 0) out[e] = p;
}

extern "C" void kernel_launch(void* const* d_in, const int* in_sizes, int n_in,
                              void* d_out, int out_size, void* d_ws, size_t ws_size,
                              hipStream_t stream) {
    const float* x   = (const float*)d_in[0];
    const int*   ei  = (const int*)d_in[1];   // [2,E] flat: src = ei, dst = ei+E
    const float* ew  = (const float*)d_in[2];
    const int*   eli = (const int*)d_in[3];   // [2,L] flat
    const float* W1  = (const float*)d_in[4];
    const float* b1  = (const float*)d_in[5];
    const float* W2  = (const float*)d_in[6];
    const float* b2  = (const float*)d_in[7];
    float* out = (float*)d_out;

    const int N = in_sizes[0] / 128;
    const int E = in_sizes[2];
    const int L = in_sizes[3] / 2;
    const int NP = ((N + 255) / 256) * 256;

    float* ws     = (float*)d_ws;
    float* dinv   = ws;                                  // NP
    int*   cnt    = (int*)(ws + NP);                     // NP (needs N+1)
    int*   rowptr = cnt + NP;                            // NP (needs N+1)
    int*   pos    = rowptr + NP;                         // NP
    int*   bsum   = pos + NP;                            // 1024
    int*   s_srt  = bsum + 1024;                         // E
    float* n_srt  = (float*)(s_srt + E);                 // E
    float* A      = n_srt + E;                           // NP*128
    float* B      = A + (size_t)NP * 128;                // NP*128

    const int n1 = N + 1;
    const int nb = (n1 + 1023) / 1024;

    hipMemsetAsync(dinv, 0, (size_t)N * 4, stream);
    hipMemsetAsync(cnt, 0, (size_t)n1 * 4, stream);
    deg_hist_kernel<<<(E + 255) / 256, 256, 0, stream>>>(ei + E, ew, dinv, cnt, E);
    dinv_kernel<<<(N + 255) / 256, 256, 0, stream>>>(dinv, N);

    scan_block<<<nb, 256, 0, stream>>>(cnt, rowptr, bsum, n1);
    scan_bsums<<<1, 256, 0, stream>>>(bsum, nb);
    scan_add<<<(n1 + 255) / 256, 256, 0, stream>>>(rowptr, bsum, n1);
    copy_int<<<(N + 255) / 256, 256, 0, stream>>>(rowptr, pos, N);
    build_csr<<<(E + 255) / 256, 256, 0, stream>>>(ei, ei + E, ew, dinv, pos, s_srt, n_srt, E);

    // layer 1
    gemm_rt<128><<<(N + 63) / 64, 256, 0, stream>>>(x, W1, A, N);
    gather_reduce<128, true><<<(N * 32 + 255) / 256, 256, 0, stream>>>(A, rowptr, s_srt, n_srt, dinv, b1, B, N);

    // layer 2
    gemm_rt<64><<<(N + 63) / 64, 256, 0, stream>>>(B, W2, A, N);
    gather_reduce<64, false><<<(N * 16 + 255) / 256, 256, 0, stream>>>(A, rowptr, s_srt, n_srt, dinv, b2, B, N);

    // decode
    decode_kernel<<<(L * 16 + 255) / 256, 256, 0, stream>>>(B, eli, eli + L, out, L);
}

// Round 5
// 522.121 us; speedup vs baseline: 8.6500x; 1.2232x over previous
//
#include <hip/hip_runtime.h>
#include <math.h>

// ---------------- histogram + in-bucket rank (the ONLY heavy atomic pass) ----------------
__global__ void hist_rank_kernel(const int* __restrict__ dst, int* __restrict__ cnt,
                                 int* __restrict__ rank, int E) {
    int t = blockIdx.x * blockDim.x + threadIdx.x;
    if (t < E) rank[t] = atomicAdd(&cnt[dst[t]], 1);
}

// exclusive scan, stage 1
__global__ __launch_bounds__(256) void scan_block(const int* __restrict__ in, int* __restrict__ out,
                                                  int* __restrict__ bsum, int n) {
    __shared__ int s[256];
    int tid = threadIdx.x;
    int base = blockIdx.x * 1024 + tid * 4;
    int a0 = (base + 0 < n) ? in[base + 0] : 0;
    int a1 = (base + 1 < n) ? in[base + 1] : 0;
    int a2 = (base + 2 < n) ? in[base + 2] : 0;
    int a3 = (base + 3 < n) ? in[base + 3] : 0;
    int tsum = a0 + a1 + a2 + a3;
    s[tid] = tsum;
    __syncthreads();
    for (int off = 1; off < 256; off <<= 1) {
        int v = (tid >= off) ? s[tid - off] : 0;
        __syncthreads();
        s[tid] += v;
        __syncthreads();
    }
    int texcl = s[tid] - tsum;
    if (base + 0 < n) out[base + 0] = texcl;
    if (base + 1 < n) out[base + 1] = texcl + a0;
    if (base + 2 < n) out[base + 2] = texcl + a0 + a1;
    if (base + 3 < n) out[base + 3] = texcl + a0 + a1 + a2;
    if (tid == 255) bsum[blockIdx.x] = s[255];
}

// stage 2: exclusive scan of block sums
__global__ __launch_bounds__(256) void scan_bsums(int* __restrict__ bsum, int nb) {
    __shared__ int s[256];
    __shared__ int carry_s;
    int tid = threadIdx.x;
    if (tid == 0) carry_s = 0;
    __syncthreads();
    for (int base = 0; base < nb; base += 256) {
        int v = (base + tid < nb) ? bsum[base + tid] : 0;
        int orig = v;
        s[tid] = v;
        __syncthreads();
        for (int off = 1; off < 256; off <<= 1) {
            int u = (tid >= off) ? s[tid - off] : 0;
            __syncthreads();
            s[tid] += u;
            __syncthreads();
        }
        int carry = carry_s;
        int excl = s[tid] - orig + carry;
        if (base + tid < nb) bsum[base + tid] = excl;
        int tot = s[255];
        __syncthreads();
        if (tid == 0) carry_s = carry + tot;
        __syncthreads();
    }
}

// stage 3: add block offsets
__global__ void scan_add(int* __restrict__ rowptr, const int* __restrict__ bscan, int n) {
    int t = blockIdx.x * blockDim.x + threadIdx.x;
    if (t < n) rowptr[t] += bscan[t >> 10];
}

// atomic-free CSR placement: pairs[rowptr[d] + rank[e]] = (src, ew)
__global__ void scatter_pairs(const int* __restrict__ src, const int* __restrict__ dst,
                              const float* __restrict__ ew, const int* __restrict__ rowptr,
                              const int* __restrict__ rank, int2* __restrict__ pairs, int E) {
    int e = blockIdx.x * blockDim.x + threadIdx.x;
    if (e >= E) return;
    int d = dst[e];
    int p = rowptr[d] + rank[e];
    pairs[p] = make_int2(src[e], __float_as_int(ew[e]));
}

// degree from sequential segment sum of sorted ew; dinv = 1/sqrt(deg+1)
__global__ void deg_dinv_kernel(const int2* __restrict__ pairs, const int* __restrict__ rowptr,
                                float* __restrict__ dinv, int n) {
    int i = blockIdx.x * blockDim.x + threadIdx.x;
    if (i >= n) return;
    int beg = rowptr[i], end = rowptr[i + 1];
    float s = 0.f;
    for (int j = beg; j < end; j++) s += __int_as_float(pairs[j].y);
    dinv[i] = 1.0f / sqrtf(s + 1.0f);   // self-loop weight folded in
}

// w' = dinv[src] * ew  (dinv[dst] factored out, applied in gather epilogue)
__global__ void norm_kernel(int2* __restrict__ pairs, const float* __restrict__ dinv, int E) {
    int j = blockIdx.x * blockDim.x + threadIdx.x;
    if (j >= E) return;
    int2 pr = pairs[j];
    pairs[j].y = __float_as_int(__int_as_float(pr.y) * dinv[pr.x]);
}

// ---------------- register-tiled GEMM: Y[n,OUT] = X[n,128] @ W[128,OUT] ----------------
template<int OUT>
__global__ __launch_bounds__(256) void gemm_rt(const float* __restrict__ X,
                                               const float* __restrict__ W,
                                               float* __restrict__ Y, int n) {
    constexpr int CG  = OUT / 4;
    constexpr int RG  = 256 / CG;
    constexpr int M   = 64;
    constexpr int RT  = M / RG;
    constexpr int KC  = 32;
    constexpr int LDX = 132;
    __shared__ float  Xl[M * LDX];
    __shared__ float4 Wl[KC * CG];

    int t = threadIdx.x;
    int row0 = blockIdx.x * M;

    {
        const float4* Xg = (const float4*)X;
        for (int f = t; f < M * 32; f += 256) {
            int r = f >> 5, c4 = f & 31;
            int gr = row0 + r;
            float4 v = make_float4(0.f, 0.f, 0.f, 0.f);
            if (gr < n) v = Xg[(size_t)gr * 32 + c4];
            *(float4*)&Xl[r * LDX + c4 * 4] = v;
        }
    }

    int cg = t % CG;
    int r0 = (t / CG) * RT;

    float4 acc[RT];
#pragma unroll
    for (int r = 0; r < RT; r++) acc[r] = make_float4(0.f, 0.f, 0.f, 0.f);

    const float4* Wg = (const float4*)W;
    for (int kc = 0; kc < 128; kc += KC) {
        __syncthreads();
        for (int f = t; f < KC * CG; f += 256)
            Wl[f] = Wg[(size_t)kc * CG + f];
        __syncthreads();
#pragma unroll 4
        for (int k = 0; k < KC; k += 4) {
            float4 b0 = Wl[(k + 0) * CG + cg];
            float4 b1 = Wl[(k + 1) * CG + cg];
            float4 b2 = Wl[(k + 2) * CG + cg];
            float4 b3 = Wl[(k + 3) * CG + cg];
#pragma unroll
            for (int r = 0; r < RT; r++) {
                float4 a = *(float4*)&Xl[(r0 + r) * LDX + kc + k];
                acc[r].x += a.x * b0.x + a.y * b1.x + a.z * b2.x + a.w * b3.x;
                acc[r].y += a.x * b0.y + a.y * b1.y + a.z * b2.y + a.w * b3.y;
                acc[r].z += a.x * b0.z + a.y * b1.z + a.z * b2.z + a.w * b3.z;
                acc[r].w += a.x * b0.w + a.y * b1.w + a.z * b2.w + a.w * b3.w;
            }
        }
    }

#pragma unroll
    for (int r = 0; r < RT; r++) {
        int gr = row0 + r0 + r;
        if (gr < n) *(float4*)&Y[(size_t)gr * OUT + cg * 4] = acc[r];
    }
}

// ---------------- CSR segmented gather-reduce, 4x unrolled ----------------
// out = di*(sum_j w'_j H[s_j] + di*H[node]) + bias,  w' = dinv[src]*ew
template<int C, bool RELU>
__global__ __launch_bounds__(256) void gather_reduce(const float* __restrict__ H,
                                                     const int* __restrict__ rowptr,
                                                     const int2* __restrict__ pairs,
                                                     const float* __restrict__ dinv,
                                                     const float* __restrict__ bias,
                                                     float* __restrict__ out, int n) {
    constexpr int TPN = C / 4;
    int t = blockIdx.x * blockDim.x + threadIdx.x;
    int node = t / TPN;
    int c = (t % TPN) * 4;
    if (node >= n) return;
    int beg = rowptr[node], end = rowptr[node + 1];
    float di = dinv[node];
    float4 hv = *(const float4*)&H[(size_t)node * C + c];
    float4 bb = *(const float4*)&bias[c];
    float4 a0, a1, a2, a3;
    a0.x = hv.x * di;
    a0.y = hv.y * di;
    a0.z = hv.z * di;
    a0.w = hv.w * di;
    a1 = make_float4(0.f, 0.f, 0.f, 0.f);
    a2 = make_float4(0.f, 0.f, 0.f, 0.f);
    a3 = make_float4(0.f, 0.f, 0.f, 0.f);
    int j = beg;
    for (; j + 4 <= end; j += 4) {
        int2 p0 = pairs[j + 0], p1 = pairs[j + 1], p2 = pairs[j + 2], p3 = pairs[j + 3];
        float4 v0 = *(const float4*)&H[(size_t)p0.x * C + c];
        float4 v1 = *(const float4*)&H[(size_t)p1.x * C + c];
        float4 v2 = *(const float4*)&H[(size_t)p2.x * C + c];
        float4 v3 = *(const float4*)&H[(size_t)p3.x * C + c];
        float w0 = __int_as_float(p0.y), w1 = __int_as_float(p1.y);
        float w2 = __int_as_float(p2.y), w3 = __int_as_float(p3.y);
        a0.x += v0.x * w0; a0.y += v0.y * w0; a0.z += v0.z * w0; a0.w += v0.w * w0;
        a1.x += v1.x * w1; a1.y += v1.y * w1; a1.z += v1.z * w1; a1.w += v1.w * w1;
        a2.x += v2.x * w2; a2.y += v2.y * w2; a2.z += v2.z * w2; a2.w += v2.w * w2;
        a3.x += v3.x * w3; a3.y += v3.y * w3; a3.z += v3.z * w3; a3.w += v3.w * w3;
    }
    for (; j < end; j++) {
        int2 pr = pairs[j];
        float w = __int_as_float(pr.y);
        float4 v = *(const float4*)&H[(size_t)pr.x * C + c];
        a0.x += v.x * w; a0.y += v.y * w; a0.z += v.z * w; a0.w += v.w * w;
    }
    float4 acc;
    acc.x = ((a0.x + a1.x) + (a2.x + a3.x)) * di + bb.x;
    acc.y = ((a0.y + a1.y) + (a2.y + a3.y)) * di + bb.y;
    acc.z = ((a0.z + a1.z) + (a2.z + a3.z)) * di + bb.z;
    acc.w = ((a0.w + a1.w) + (a2.w + a3.w)) * di + bb.w;
    if (RELU) {
        acc.x = fmaxf(acc.x, 0.f);
        acc.y = fmaxf(acc.y, 0.f);
        acc.z = fmaxf(acc.z, 0.f);
        acc.w = fmaxf(acc.w, 0.f);
    }
    *(float4*)&out[(size_t)node * C + c] = acc;
}

// ---------------- decode ----------------
__global__ void decode_kernel(const float* __restrict__ Z, const int* __restrict__ ea,
                              const int* __restrict__ eb, float* __restrict__ out, int L) {
    int t = blockIdx.x * blockDim.x + threadIdx.x;
    int e = t >> 4;
    int c = (t & 15) << 2;
    if (e >= L) return;
    float4 za = *(const float4*)&Z[(size_t)ea[e] * 64 + c];
    float4 zb = *(const float4*)&Z[(size_t)eb[e] * 64 + c];
    float p = za.x * zb.x + za.y * zb.y + za.z * zb.z + za.w * zb.w;
    p += __shfl_xor(p, 1);
    p += __shfl_xor(p, 2);
    p += __shfl_xor(p, 4);
    p += __shfl_xor(p, 8);
    if ((t & 15) == 0) out[e] = p;
}

extern "C" void kernel_launch(void* const* d_in, const int* in_sizes, int n_in,
                              void* d_out, int out_size, void* d_ws, size_t ws_size,
                              hipStream_t stream) {
    const float* x   = (const float*)d_in[0];
    const int*   ei  = (const int*)d_in[1];   // [2,E] flat: src = ei, dst = ei+E
    const float* ew  = (const float*)d_in[2];
    const int*   eli = (const int*)d_in[3];   // [2,L] flat
    const float* W1  = (const float*)d_in[4];
    const float* b1  = (const float*)d_in[5];
    const float* W2  = (const float*)d_in[6];
    const float* b2  = (const float*)d_in[7];
    float* out = (float*)d_out;

    const int N = in_sizes[0] / 128;
    const int E = in_sizes[2];
    const int L = in_sizes[3] / 2;
    const int NP = ((N + 255) / 256) * 256;

    // ws layout (4B words); pairs needs 8B alignment (offsets are multiples of 256)
    float* ws     = (float*)d_ws;
    float* dinv   = ws;                                  // NP
    int*   cnt    = (int*)(ws + NP);                     // NP (needs N+1)
    int*   rowptr = cnt + NP;                            // NP (needs N+1)
    int*   bsum   = rowptr + NP;                         // 1024
    int*   rank   = bsum + 1024;                         // E
    int2*  pairs  = (int2*)(rank + E);                   // E int2 (8B each)
    float* A      = (float*)(pairs + E);                 // NP*128
    float* B      = A + (size_t)NP * 128;                // NP*128

    const int n1 = N + 1;
    const int nb = (n1 + 1023) / 1024;

    // CSR build: 1 atomic pass + scan + deterministic scatter
    hipMemsetAsync(cnt, 0, (size_t)n1 * 4, stream);
    hist_rank_kernel<<<(E + 255) / 256, 256, 0, stream>>>(ei + E, cnt, rank, E);
    scan_block<<<nb, 256, 0, stream>>>(cnt, rowptr, bsum, n1);
    scan_bsums<<<1, 256, 0, stream>>>(bsum, nb);
    scan_add<<<(n1 + 255) / 256, 256, 0, stream>>>(rowptr, bsum, n1);
    scatter_pairs<<<(E + 255) / 256, 256, 0, stream>>>(ei, ei + E, ew, rowptr, rank, pairs, E);
    deg_dinv_kernel<<<(N + 255) / 256, 256, 0, stream>>>(pairs, rowptr, dinv, N);
    norm_kernel<<<(E + 255) / 256, 256, 0, stream>>>(pairs, dinv, E);

    // layer 1
    gemm_rt<128><<<(N + 63) / 64, 256, 0, stream>>>(x, W1, A, N);
    gather_reduce<128, true><<<(N * 32 + 255) / 256, 256, 0, stream>>>(A, rowptr, pairs, dinv, b1, B, N);

    // layer 2
    gemm_rt<64><<<(N + 63) / 64, 256, 0, stream>>>(B, W2, A, N);
    gather_reduce<64, false><<<(N * 16 + 255) / 256, 256, 0, stream>>>(A, rowptr, pairs, dinv, b2, B, N);

    // decode
    decode_kernel<<<(L * 16 + 255) / 256, 256, 0, stream>>>(B, eli, eli + L, out, L);
}